// Round 9
// baseline (775.562 us; speedup 1.0000x reference)
//
#include <hip/hip_runtime.h>
#include <math.h>

#define Mtot 4096   // B*T
#define Dd   512
#define Hh   8
#define DKk  64
#define TT   1024
#define Ff   2048
#define Ll   4
#define Vv   32000

typedef __attribute__((ext_vector_type(8))) short bf16x8;
typedef __attribute__((ext_vector_type(4))) float f32x4;
typedef unsigned short u16;

__device__ __forceinline__ u16 f2b(float f) {
    union { float f; unsigned u; } x; x.f = f;
    unsigned r = x.u + 0x7fffu + ((x.u >> 16) & 1u);
    return (u16)(r >> 16);
}

typedef const __attribute__((address_space(1))) unsigned int* gp_t;
typedef __attribute__((address_space(3))) unsigned int* lp_t;
#define GLOAD_LDS16(g, l) __builtin_amdgcn_global_load_lds((gp_t)(const void*)(g), (lp_t)(void*)(l), 16, 0, 0)
#define SBAR  __builtin_amdgcn_s_barrier()
#define SCHED0 __builtin_amdgcn_sched_barrier(0)

// attention LDS swizzle (u16-index space; rows are 64 bf16 = 128 B)
#define SWZ(row, c)  ((c) ^ (((row) & 7) << 3))

// ---------------- fused prep: weight transposes + bias pack + embed+PE ----------------
__global__ __launch_bounds__(256) void prep_kernel(const float* __restrict__ Wq, const float* __restrict__ Wk,
                                                   const float* __restrict__ Wv, const float* __restrict__ Wo,
                                                   const float* __restrict__ W1, const float* __restrict__ W2,
                                                   const float* __restrict__ Wl,
                                                   u16* __restrict__ WqkvT, u16* __restrict__ WoT,
                                                   u16* __restrict__ W1T, u16* __restrict__ W2T,
                                                   u16* __restrict__ WlT,
                                                   const float* __restrict__ bq, const float* __restrict__ bk,
                                                   const float* __restrict__ bv, float* __restrict__ bqkv,
                                                   const int* __restrict__ x, const float* __restrict__ emw,
                                                   float* __restrict__ h, u16* __restrict__ hb) {
    int id = blockIdx.x;
    if (id >= 28312) {            // ---- embed + positional encoding (8192 blocks) ----
        int idx = (id - 28312) * 256 + threadIdx.x;
        int d  = idx & (Dd - 1);
        int bt = idx >> 9;
        int t  = bt & (TT - 1);
        int tok = x[bt];
        float val = (tok == 0) ? 0.0f : emw[(size_t)tok * Dd + d];
        int de = d & ~1;
        float ang = (float)t * expf((float)de * (-9.210340371976184f / (float)Dd));
        val += (d & 1) ? cosf(ang) : sinf(ang);
        h[idx] = val;
        hb[idx] = f2b(val);
        return;
    }
    if (id >= 28288) {            // ---- bias pack (24 blocks) ----
        int idx = (id - 28288) * 256 + threadIdx.x;
        int l = idx / 1536, j = idx - l * 1536;
        float v = (j < 512) ? bq[l * 512 + j] : (j < 1024) ? bk[l * 512 + j - 512] : bv[l * 512 + j - 1024];
        bqkv[idx] = v;
        return;
    }
    // ---- weight transpose: src[K][N] f32 -> dst[N][K] bf16 ----
    __shared__ float t[32][33];
    const float* src; u16* dst; int K, N, tx, ty;
    if (id < 12288) {
        int l = id / 3072, r = id - l * 3072;
        if (r < 768) {
            int which = r >> 8, t2 = r & 255;
            src = (which == 0 ? Wq : which == 1 ? Wk : Wv) + (size_t)l * 262144;
            dst = WqkvT + (size_t)l * 786432 + (size_t)which * 262144;
            K = 512; N = 512; ty = t2 >> 4; tx = t2 & 15;
        } else if (r < 1024) {
            int t2 = r - 768;
            src = Wo + (size_t)l * 262144; dst = WoT + (size_t)l * 262144;
            K = 512; N = 512; ty = t2 >> 4; tx = t2 & 15;
        } else if (r < 2048) {
            int t2 = r - 1024;
            src = W1 + (size_t)l * 1048576; dst = W1T + (size_t)l * 1048576;
            K = 512; N = 2048; ty = t2 >> 6; tx = t2 & 63;
        } else {
            int t2 = r - 2048;
            src = W2 + (size_t)l * 1048576; dst = W2T + (size_t)l * 1048576;
            K = 2048; N = 512; ty = t2 >> 4; tx = t2 & 15;
        }
    } else {
        int t2 = id - 12288;
        src = Wl; dst = WlT; K = 512; N = 32000;
        ty = t2 / 1000; tx = t2 - ty * 1000;
    }
    int n0 = tx * 32, k0 = ty * 32;
    int tid = threadIdx.x, c = tid & 31, rr = tid >> 5;
    #pragma unroll
    for (int i = 0; i < 4; i++)
        t[rr + i * 8][c] = src[(size_t)(k0 + rr + i * 8) * N + n0 + c];
    __syncthreads();
    #pragma unroll
    for (int i = 0; i < 4; i++)
        dst[(size_t)(n0 + rr + i * 8) * K + k0 + c] = f2b(t[c][rr + i * 8]);
}

// ---------------- bf16 MFMA GEMM v3: 4 waves, 128x128 tile, BK=64, ring-2 counted-vmcnt ----------------
// Operand-swapped MFMA: lane holds 1 M-row x 4 consecutive N-cols per fragment -> vectorized C-stores.
template<int ACT, int OUTB, int QKVMODE, int SPLITK>
__global__ __launch_bounds__(256, 2) void mfma_gemm(const u16* __restrict__ A,
                                                    const u16* __restrict__ BT,
                                                    const float* __restrict__ bias,
                                                    float* __restrict__ outF,
                                                    u16* __restrict__ outB,
                                                    u16* __restrict__ vtb,
                                                    int M, int N, int K, int gx, int PS) {
    __shared__ __align__(16) u16 As[2][128 * 64];
    __shared__ __align__(16) u16 Bs[2][128 * 64];
    int tid = threadIdx.x;
    int lane = tid & 63, w = tid >> 6;
    int nwg = gridDim.x, flat = blockIdx.x;
    int wg = (flat & 7) * (nwg >> 3) + (flat >> 3);   // bijective XCD swizzle (nwg%8==0)
    int ks = 0, sub = wg;
    if (SPLITK > 1) {
        int tps = gx * (M >> 7);
        ks = wg / tps; sub = wg - ks * tps;
    }
    int bm = sub / gx, bn = sub - bm * gx;
    int kb = ks * (K / SPLITK);
    int wr = w >> 1, wc = w & 1;                      // wave grid 2x2 -> 64x64 per wave
    int fr = lane & 15, fq = lane >> 4;

    int sr = lane >> 3, sc = lane & 7;
    int scol = (sc ^ sr) * 8;                         // pre-swizzled source chunk
    const u16* Ab = A  + (size_t)(bm * 128 + w * 32 + sr) * K + kb + scol;
    const u16* Bb = BT + (size_t)(bn * 128 + w * 32 + sr) * K + kb + scol;
    u16* lA = &As[0][0] + w * 2048;
    u16* lB = &Bs[0][0] + w * 2048;

    f32x4 acc[4][4] = {};
    int nk = (K / SPLITK) >> 6;

#define STAGE(buf, kt)                                                     \
    {   int ko = (kt) * 64;                                                \
        GLOAD_LDS16(Ab + ko,          lA + (buf) * (128 * 64));            \
        GLOAD_LDS16(Ab + 8 * K + ko,  lA + (buf) * (128 * 64) + 512);      \
        GLOAD_LDS16(Ab + 16 * K + ko, lA + (buf) * (128 * 64) + 1024);     \
        GLOAD_LDS16(Ab + 24 * K + ko, lA + (buf) * (128 * 64) + 1536);     \
        GLOAD_LDS16(Bb + ko,          lB + (buf) * (128 * 64));            \
        GLOAD_LDS16(Bb + 8 * K + ko,  lB + (buf) * (128 * 64) + 512);      \
        GLOAD_LDS16(Bb + 16 * K + ko, lB + (buf) * (128 * 64) + 1024);     \
        GLOAD_LDS16(Bb + 24 * K + ko, lB + (buf) * (128 * 64) + 1536); }

    STAGE(0, 0);
    STAGE(1, 1);

    int cur = 0;
    for (int kt = 0; kt < nk; kt++) {
        if (kt + 1 < nk) { asm volatile("s_waitcnt vmcnt(8)" ::: "memory"); }
        else             { asm volatile("s_waitcnt vmcnt(0)" ::: "memory"); }
        SBAR;
        SCHED0;
        bf16x8 a[4][2], b[4][2];
        #pragma unroll
        for (int m = 0; m < 4; m++) {
            int row = wr * 64 + m * 16 + fr;
            a[m][0] = *(const bf16x8*)&As[cur][row * 64 + ((fq ^ (row & 7)) * 8)];
            a[m][1] = *(const bf16x8*)&As[cur][row * 64 + (((fq + 4) ^ (row & 7)) * 8)];
        }
        #pragma unroll
        for (int n = 0; n < 4; n++) {
            int row = wc * 64 + n * 16 + fr;
            b[n][0] = *(const bf16x8*)&Bs[cur][row * 64 + ((fq ^ (row & 7)) * 8)];
            b[n][1] = *(const bf16x8*)&Bs[cur][row * 64 + (((fq + 4) ^ (row & 7)) * 8)];
        }
        __builtin_amdgcn_s_setprio(1);
        #pragma unroll
        for (int m = 0; m < 4; m++)
            #pragma unroll
            for (int n = 0; n < 4; n++) {
                acc[m][n] = __builtin_amdgcn_mfma_f32_16x16x32_bf16(b[n][0], a[m][0], acc[m][n], 0, 0, 0);
                acc[m][n] = __builtin_amdgcn_mfma_f32_16x16x32_bf16(b[n][1], a[m][1], acc[m][n], 0, 0, 0);
            }
        __builtin_amdgcn_s_setprio(0);
        SCHED0;
        SBAR;
        SCHED0;
        if (kt + 2 < nk) STAGE(cur, kt + 2);
        cur ^= 1;
    }
#undef STAGE

    // epilogue: lane owns M-row = ...+m*16+fr, N-cols = ...+n*16+fq*4 .. +3
    #pragma unroll
    for (int m = 0; m < 4; m++) {
        int row = bm * 128 + wr * 64 + m * 16 + fr;
        #pragma unroll
        for (int n = 0; n < 4; n++) {
            int col0 = bn * 128 + wc * 64 + n * 16 + fq * 4;
            if (QKVMODE && bn >= 8) {                  // V columns -> transposed scatter
                int bb = row >> 10, t = row & 1023;
                #pragma unroll
                for (int r = 0; r < 4; r++) {
                    int d = col0 + r - 1024;
                    int hh = d >> 6, dd = d & 63;
                    vtb[(((size_t)bb * Hh + hh) * 64 + dd) * 1024 + t] = f2b(acc[m][n][r] + bias[col0 + r]);
                }
            } else {
                f32x4 v = acc[m][n];
                if (bias && ks == 0) v += *(const f32x4*)&bias[col0];
                if (ACT == 1) {
                    #pragma unroll
                    for (int r = 0; r < 4; r++) v[r] = 0.5f * v[r] * (1.0f + erff(v[r] * 0.7071067811865475f));
                }
                if (OUTB) {
                    union { unsigned long long ull; u16 s[4]; } pk;
                    #pragma unroll
                    for (int r = 0; r < 4; r++) pk.s[r] = f2b(v[r]);
                    *(unsigned long long*)&outB[(size_t)row * N + col0] = pk.ull;
                } else {
                    *(f32x4*)&outF[(size_t)ks * PS + (size_t)row * N + col0] = v;
                }
            }
        }
    }
}

// ---------------- bf16 MFMA GEMM 256x256: 8 waves, BK=64, ring-2 (logits) ----------------
__global__ __launch_bounds__(512, 1) void mfma_gemm256(const u16* __restrict__ A,
                                                       const u16* __restrict__ BT,
                                                       const float* __restrict__ bias,
                                                       float* __restrict__ outF,
                                                       int M, int N, int K, int gy) {
    __shared__ __align__(16) u16 As[2][256 * 64];
    __shared__ __align__(16) u16 Bs[2][256 * 64];
    int tid = threadIdx.x;
    int lane = tid & 63, w = tid >> 6;
    int nwg = gridDim.x, flat = blockIdx.x;
    int wg = (flat & 7) * (nwg >> 3) + (flat >> 3);
    int bm = wg & (gy - 1), bn = wg >> 4;             // column-major (gy==16)
    int wr = w >> 2, wc = w & 3;
    int fr = lane & 15, fq = lane >> 4;

    int sr8 = lane >> 3, sc = lane & 7;
    int scol = (sc ^ sr8) * 8;
    const u16* Ab = A  + (size_t)(bm * 256 + w * 32 + sr8) * K + scol;
    const u16* Bb = BT + (size_t)(bn * 256 + w * 32 + sr8) * K + scol;

    f32x4 acc[8][4] = {};
    int nk = K >> 6;

#define STAGE256(buf, kt)                                                    \
    {   int ko = (kt) * 64;                                                  \
        GLOAD_LDS16(Ab + ko,          &As[buf][(w * 32 +  0) * 64]);         \
        GLOAD_LDS16(Ab + 8 * K + ko,  &As[buf][(w * 32 +  8) * 64]);         \
        GLOAD_LDS16(Ab + 16 * K + ko, &As[buf][(w * 32 + 16) * 64]);         \
        GLOAD_LDS16(Ab + 24 * K + ko, &As[buf][(w * 32 + 24) * 64]);         \
        GLOAD_LDS16(Bb + ko,          &Bs[buf][(w * 32 +  0) * 64]);         \
        GLOAD_LDS16(Bb + 8 * K + ko,  &Bs[buf][(w * 32 +  8) * 64]);         \
        GLOAD_LDS16(Bb + 16 * K + ko, &Bs[buf][(w * 32 + 16) * 64]);         \
        GLOAD_LDS16(Bb + 24 * K + ko, &Bs[buf][(w * 32 + 24) * 64]); }

    STAGE256(0, 0);
    STAGE256(1, 1);

    int cur = 0;
    for (int kt = 0; kt < nk; kt++) {
        if (kt + 1 < nk) { asm volatile("s_waitcnt vmcnt(8)" ::: "memory"); }
        else             { asm volatile("s_waitcnt vmcnt(0)" ::: "memory"); }
        SBAR;
        SCHED0;
        bf16x8 b[4][2];
        #pragma unroll
        for (int n = 0; n < 4; n++) {
            int row = wc * 64 + n * 16 + fr;
            b[n][0] = *(const bf16x8*)&Bs[cur][row * 64 + ((fq ^ (row & 7)) * 8)];
            b[n][1] = *(const bf16x8*)&Bs[cur][row * 64 + (((fq + 4) ^ (row & 7)) * 8)];
        }
        #pragma unroll
        for (int m = 0; m < 8; m++) {
            int row = wr * 128 + m * 16 + fr;
            bf16x8 a0 = *(const bf16x8*)&As[cur][row * 64 + ((fq ^ (row & 7)) * 8)];
            bf16x8 a1 = *(const bf16x8*)&As[cur][row * 64 + (((fq + 4) ^ (row & 7)) * 8)];
            __builtin_amdgcn_s_setprio(1);
            #pragma unroll
            for (int n = 0; n < 4; n++) {
                acc[m][n] = __builtin_amdgcn_mfma_f32_16x16x32_bf16(b[n][0], a0, acc[m][n], 0, 0, 0);
                acc[m][n] = __builtin_amdgcn_mfma_f32_16x16x32_bf16(b[n][1], a1, acc[m][n], 0, 0, 0);
            }
            __builtin_amdgcn_s_setprio(0);
        }
        SCHED0;
        SBAR;
        SCHED0;
        if (kt + 2 < nk) STAGE256(cur, kt + 2);
        cur ^= 1;
    }
#undef STAGE256

    #pragma unroll
    for (int m = 0; m < 8; m++) {
        int row = bm * 256 + wr * 128 + m * 16 + fr;
        #pragma unroll
        for (int n = 0; n < 4; n++) {
            int col0 = bn * 256 + wc * 64 + n * 16 + fq * 4;
            f32x4 v = acc[m][n] + *(const f32x4*)&bias[col0];
            *(f32x4*)&outF[(size_t)row * N + col0] = v;
        }
    }
}

// ---------------- MFMA flash attention: QBLK=128 (8 waves x 16 rows), KVBLK=64 ----------------
// 512 threads: tid<256 stage K tiles, tid>=256 stage V tiles (unified base + kt*kstep).
__global__ __launch_bounds__(512) void attn_mfma(const u16* __restrict__ qkv,
                                                 const u16* __restrict__ vtb,
                                                 u16* __restrict__ ob) {
    int qt = (int)gridDim.x - 1 - (int)blockIdx.x;   // heavy blocks first
    int hh = blockIdx.y, b = blockIdx.z;
    __shared__ __align__(16) u16 Qs[128 * 64];
    __shared__ __align__(16) u16 Ks[64 * 64];
    __shared__ __align__(16) u16 Vs[64 * 64];        // rows = d, cols = t
    __shared__ __align__(16) u16 Ps[8][16 * 64];
    int tid = threadIdx.x;
    int lane = tid & 63, w = tid >> 6;
    int fr = lane & 15, fq = lane >> 4;
    int q0 = qt * 128;
    int nkt = 2 * qt + 2;

    // K/V staging role: kv=0 -> K rows (t-major), kv=1 -> V rows (d-major from vtb)
    int kv = tid >> 8;
    int rr = (tid & 255) >> 2, cc = ((tid & 255) & 3) * 16;
    const u16* kvbase;
    size_t kstep;
    if (kv == 0) { kvbase = qkv + ((size_t)(b * TT + rr)) * 1536 + 512 + hh * 64 + cc; kstep = (size_t)64 * 1536; }
    else         { kvbase = vtb + (((size_t)(b * Hh + hh)) * 64 + rr) * 1024 + cc;     kstep = 64; }
    u16* lds0 = (kv ? Vs : Ks) + rr * 64 + SWZ(rr, cc);
    u16* lds1 = (kv ? Vs : Ks) + rr * 64 + SWZ(rr, cc + 8);

    bf16x8 r0, r1, s0, s1;   // ping-pong prefetch regs
    auto load_cur = [&](int kt) { const u16* p = kvbase + (size_t)kt * kstep; r0 = *(const bf16x8*)p; r1 = *(const bf16x8*)(p + 8); };
    auto load_nxt = [&](int kt) { const u16* p = kvbase + (size_t)kt * kstep; s0 = *(const bf16x8*)p; s1 = *(const bf16x8*)(p + 8); };
    auto store_cur = [&]() { *(bf16x8*)lds0 = r0; *(bf16x8*)lds1 = r1; };
    auto store_nxt = [&]() { *(bf16x8*)lds0 = s0; *(bf16x8*)lds1 = s1; };

    load_cur(0);
    {   // stage Q [128][64] swizzled (512 threads, 4/row)
        int r = tid >> 2, c0 = (tid & 3) * 16;
        const u16* src = qkv + ((size_t)(b * TT + q0 + r)) * 1536 + hh * 64 + c0;
        bf16x8 v0 = *(const bf16x8*)src;
        bf16x8 v1 = *(const bf16x8*)(src + 8);
        *(bf16x8*)&Qs[r * 64 + SWZ(r, c0)]     = v0;
        *(bf16x8*)&Qs[r * 64 + SWZ(r, c0 + 8)] = v1;
    }
    __syncthreads();
    bf16x8 aq0 = *(const bf16x8*)&Qs[(w * 16 + fr) * 64 + SWZ(w * 16 + fr, fq * 8)];
    bf16x8 aq1 = *(const bf16x8*)&Qs[(w * 16 + fr) * 64 + SWZ(w * 16 + fr, 32 + fq * 8)];

    f32x4 oa[4] = {};
    float mreg[4], lreg[4];
    #pragma unroll
    for (int i = 0; i < 4; i++) { mreg[i] = -1e30f; lreg[i] = 0.0f; }

    auto compute_tile = [&](int kt) {
        f32x4 sa[4] = {};
        __builtin_amdgcn_s_setprio(1);
        #pragma unroll
        for (int nt = 0; nt < 4; nt++) {
            int krow = nt * 16 + fr;
            bf16x8 b0 = *(const bf16x8*)&Ks[krow * 64 + SWZ(krow, fq * 8)];
            bf16x8 b1 = *(const bf16x8*)&Ks[krow * 64 + SWZ(krow, 32 + fq * 8)];
            sa[nt] = __builtin_amdgcn_mfma_f32_16x16x32_bf16(aq0, b0, sa[nt], 0, 0, 0);
            sa[nt] = __builtin_amdgcn_mfma_f32_16x16x32_bf16(aq1, b1, sa[nt], 0, 0, 0);
        }
        __builtin_amdgcn_s_setprio(0);

        // global causal mask every tile: kg = kt*64 + nt*16+fr ; qg = q0 + w*16 + fq*4 + i
        float p[4][4];
        int qgb = q0 + w * 16 + fq * 4;
        int kgb = kt * 64 + fr;
        #pragma unroll
        for (int nt = 0; nt < 4; nt++)
            #pragma unroll
            for (int i = 0; i < 4; i++) {
                float s = sa[nt][i] * 0.125f;
                if (kgb + nt * 16 > qgb + i) s = -1e30f;
                p[nt][i] = s;
            }

        float mnew[4], fscale[4];
        #pragma unroll
        for (int i = 0; i < 4; i++) {
            float v = fmaxf(fmaxf(p[0][i], p[1][i]), fmaxf(p[2][i], p[3][i]));
            v = fmaxf(v, __shfl_xor(v, 1));
            v = fmaxf(v, __shfl_xor(v, 2));
            v = fmaxf(v, __shfl_xor(v, 4));
            v = fmaxf(v, __shfl_xor(v, 8));
            mnew[i] = fmaxf(mreg[i], v);
            fscale[i] = __expf(mreg[i] - mnew[i]);
            mreg[i] = mnew[i];
        }
        #pragma unroll
        for (int i = 0; i < 4; i++) {
            float sum = 0.f;
            #pragma unroll
            for (int nt = 0; nt < 4; nt++) {
                float e = __expf(p[nt][i] - mnew[i]);
                p[nt][i] = e;
                sum += e;
            }
            sum += __shfl_xor(sum, 1);
            sum += __shfl_xor(sum, 2);
            sum += __shfl_xor(sum, 4);
            sum += __shfl_xor(sum, 8);
            lreg[i] = lreg[i] * fscale[i] + sum;
        }
        #pragma unroll
        for (int nn = 0; nn < 4; nn++)
            #pragma unroll
            for (int i = 0; i < 4; i++)
                oa[nn][i] *= fscale[i];

        u16* ps = &Ps[w][0];
        #pragma unroll
        for (int nt = 0; nt < 4; nt++)
            #pragma unroll
            for (int i = 0; i < 4; i++) {
                int row = fq * 4 + i, col = nt * 16 + fr;
                ps[row * 64 + SWZ(row, col)] = f2b(p[nt][i]);
            }
        bf16x8 pa0 = *(const bf16x8*)&ps[fr * 64 + SWZ(fr, fq * 8)];
        bf16x8 pa1 = *(const bf16x8*)&ps[fr * 64 + SWZ(fr, 32 + fq * 8)];
        __builtin_amdgcn_s_setprio(1);
        #pragma unroll
        for (int nn = 0; nn < 4; nn++) {
            int drow = nn * 16 + fr;
            bf16x8 vb0 = *(const bf16x8*)&Vs[drow * 64 + SWZ(drow, fq * 8)];
            bf16x8 vb1 = *(const bf16x8*)&Vs[drow * 64 + SWZ(drow, 32 + fq * 8)];
            oa[nn] = __builtin_amdgcn_mfma_f32_16x16x32_bf16(pa0, vb0, oa[nn], 0, 0, 0);
            oa[nn] = __builtin_amdgcn_mfma_f32_16x16x32_bf16(pa1, vb1, oa[nn], 0, 0, 0);
        }
        __builtin_amdgcn_s_setprio(0);
    };

    int kt = 0;
    for (;;) {
        SCHED0; SBAR;
        store_cur();
        if (kt + 1 < nkt) load_nxt(kt + 1);
        asm volatile("s_waitcnt lgkmcnt(0)" ::: "memory");
        SBAR; SCHED0;
        compute_tile(kt);
        if (++kt >= nkt) break;

        SCHED0; SBAR;
        store_nxt();
        if (kt + 1 < nkt) load_cur(kt + 1);
        asm volatile("s_waitcnt lgkmcnt(0)" ::: "memory");
        SBAR; SCHED0;
        compute_tile(kt);
        if (++kt >= nkt) break;
    }

    #pragma unroll
    for (int i = 0; i < 4; i++) {
        float inv = 1.0f / lreg[i];
        size_t row = (size_t)(b * TT + q0 + w * 16 + fq * 4 + i) * Dd + hh * 64;
        #pragma unroll
        for (int nn = 0; nn < 4; nn++)
            ob[row + nn * 16 + fr] = f2b(oa[nn][i] * inv);
    }
}

// ---------------- residual add (np split-K partials) + LayerNorm (+optional 2nd LN), wave-per-row ----------------
__global__ __launch_bounds__(256) void ln_kernel(float* __restrict__ h,
                                                 const float* __restrict__ pp, int np,
                                                 const float* __restrict__ gs,
                                                 const float* __restrict__ gb,
                                                 const float* __restrict__ gs2,
                                                 const float* __restrict__ gb2,
                                                 u16* __restrict__ hb) {
    int w = threadIdx.x >> 6, lane = threadIdx.x & 63;
    int row = (blockIdx.x << 2) + w;
    size_t base = (size_t)row * Dd + lane * 8;
    const size_t PART = (size_t)Mtot * Dd;
    f32x4 v0 = *(const f32x4*)&h[base];
    f32x4 v1 = *(const f32x4*)&h[base + 4];
    for (int p = 0; p < np; p++) {
        const float* d = pp + (size_t)p * PART;
        v0 += *(const f32x4*)&d[base];
        v1 += *(const f32x4*)&d[base + 4];
    }
    float s = v0[0] + v0[1] + v0[2] + v0[3] + v1[0] + v1[1] + v1[2] + v1[3];
    #pragma unroll
    for (int st = 1; st < 64; st <<= 1) s += __shfl_xor(s, st);
    float m = s * (1.0f / Dd);
    float q = 0.f;
    #pragma unroll
    for (int j = 0; j < 4; j++) { float a = v0[j] - m, b = v1[j] - m; q += a * a + b * b; }
    #pragma unroll
    for (int st = 1; st < 64; st <<= 1) q += __shfl_xor(q, st);
    float r = rsqrtf(q * (1.0f / Dd) + 1e-5f);
    f32x4 g0 = *(const f32x4*)&gs[lane * 8],     g1 = *(const f32x4*)&gs[lane * 8 + 4];
    f32x4 c0 = *(const f32x4*)&gb[lane * 8],     c1 = *(const f32x4*)&gb[lane * 8 + 4];
    f32x4 y0, y1;
    #pragma unroll
    for (int j = 0; j < 4; j++) {
        y0[j] = (v0[j] - m) * r * g0[j] + c0[j];
        y1[j] = (v1[j] - m) * r * g1[j] + c1[j];
    }
    if (gs2) {   // fused second LayerNorm (lnf)
        float s2 = y0[0] + y0[1] + y0[2] + y0[3] + y1[0] + y1[1] + y1[2] + y1[3];
        #pragma unroll
        for (int st = 1; st < 64; st <<= 1) s2 += __shfl_xor(s2, st);
        float m2 = s2 * (1.0f / Dd);
        float q2 = 0.f;
        #pragma unroll
        for (int j = 0; j < 4; j++) { float a = y0[j] - m2, b = y1[j] - m2; q2 += a * a + b * b; }
        #pragma unroll
        for (int st = 1; st < 64; st <<= 1) q2 += __shfl_xor(q2, st);
        float r2 = rsqrtf(q2 * (1.0f / Dd) + 1e-5f);
        f32x4 h0 = *(const f32x4*)&gs2[lane * 8], h1 = *(const f32x4*)&gs2[lane * 8 + 4];
        f32x4 d0 = *(const f32x4*)&gb2[lane * 8], d1 = *(const f32x4*)&gb2[lane * 8 + 4];
        #pragma unroll
        for (int j = 0; j < 4; j++) {
            y0[j] = (y0[j] - m2) * r2 * h0[j] + d0[j];
            y1[j] = (y1[j] - m2) * r2 * h1[j] + d1[j];
        }
    }
    bf16x8 yb;
    #pragma unroll
    for (int j = 0; j < 4; j++) {
        yb[j]     = (short)f2b(y0[j]);
        yb[j + 4] = (short)f2b(y1[j]);
    }
    *(f32x4*)&h[base]     = y0;
    *(f32x4*)&h[base + 4] = y1;
    *(bf16x8*)&hb[base]   = yb;
}

extern "C" void kernel_launch(void* const* d_in, const int* in_sizes, int n_in,
                              void* d_out, int out_size, void* d_ws, size_t ws_size,
                              hipStream_t stream) {
    const int*   x     = (const int*)  d_in[0];
    const float* embed = (const float*)d_in[1];
    const float* Wq    = (const float*)d_in[2];
    const float* bq    = (const float*)d_in[3];
    const float* Wk    = (const float*)d_in[4];
    const float* bk    = (const float*)d_in[5];
    const float* Wv    = (const float*)d_in[6];
    const float* bv    = (const float*)d_in[7];
    const float* Wo    = (const float*)d_in[8];
    const float* bo    = (const float*)d_in[9];
    const float* ln1_s = (const float*)d_in[10];
    const float* ln1_b = (const float*)d_in[11];
    const float* W1    = (const float*)d_in[12];
    const float* b1    = (const float*)d_in[13];
    const float* W2    = (const float*)d_in[14];
    const float* b2    = (const float*)d_in[15];
    const float* ln2_s = (const float*)d_in[16];
    const float* ln2_b = (const float*)d_in[17];
    const float* lnf_s = (const float*)d_in[18];
    const float* lnf_b = (const float*)d_in[19];
    const float* Wl    = (const float*)d_in[20];
    const float* bl    = (const float*)d_in[21];

    // ---- workspace layout ----
    char* wp = (char*)d_ws;
    float* h    = (float*)wp;  wp += (size_t)Mtot * Dd * 4;       //  8 MB
    u16*   hb   = (u16*)wp;    wp += (size_t)Mtot * Dd * 2;       //  4 MB
    u16*   qkvb = (u16*)wp;    wp += (size_t)Mtot * 1536 * 2;     // 12.6 MB
    u16*   vtb  = (u16*)wp;    wp += (size_t)Mtot * Dd * 2;       //  4 MB  [B][H][64][1024]
    u16*   obb  = (u16*)wp;    wp += (size_t)Mtot * Dd * 2;       //  4 MB
    u16*   fbb  = (u16*)wp;    wp += (size_t)Mtot * Ff * 2;       // 16 MB
    u16*   WlT  = (u16*)wp;    wp += (size_t)Vv * Dd * 2;         // 33 MB
    float* bqkv = (float*)wp;  wp += (size_t)Ll * 1536 * 4;       // 24 KB

    // ---- transient data in d_out (dead before final logits GEMM writes it) ----
    char* op = (char*)d_out;
    u16* WqkvT = (u16*)op;  op += (size_t)Ll * 1536 * Dd * 2;
    u16* WoT   = (u16*)op;  op += (size_t)Ll * Dd * Dd * 2;
    u16* W1T   = (u16*)op;  op += (size_t)Ll * Ff * Dd * 2;
    u16* W2T   = (u16*)op;  op += (size_t)Ll * Dd * Ff * 2;
    float* pbx = (float*)op; op += (size_t)2 * Mtot * Dd * 4;     // 16 MB split-K partials

    prep_kernel<<<36504, 256, 0, stream>>>(Wq, Wk, Wv, Wo, W1, W2, Wl,
                                           WqkvT, WoT, W1T, W2T, WlT,
                                           bq, bk, bv, bqkv, x, embed, h, hb);

    const int PS = Mtot * Dd;   // fp32 elements per split partial

    for (int l = 0; l < Ll; l++) {
        mfma_gemm<0, 1, 1, 1><<<(1536 / 128) * (Mtot / 128), 256, 0, stream>>>(
            hb, WqkvT + (size_t)l * 1536 * Dd, bqkv + l * 1536, nullptr, qkvb, vtb,
            Mtot, 1536, Dd, 1536 / 128, 0);
        attn_mfma<<<dim3(TT / 128, Hh, 4), 512, 0, stream>>>(qkvb, vtb, obb);
        // O-proj: split-K=2, one dispatch, 256 blocks
        mfma_gemm<0, 0, 0, 2><<<2 * (Dd / 128) * (Mtot / 128), 256, 0, stream>>>(
            obb, WoT + (size_t)l * Dd * Dd, bo + l * Dd, pbx, nullptr, nullptr,
            Mtot, Dd, Dd, Dd / 128, PS);
        ln_kernel<<<Mtot / 4, 256, 0, stream>>>(h, pbx, 2, ln1_s + l * Dd, ln1_b + l * Dd,
                                                nullptr, nullptr, hb);
        mfma_gemm<1, 1, 0, 1><<<(Ff / 128) * (Mtot / 128), 256, 0, stream>>>(
            hb, W1T + (size_t)l * Ff * Dd, b1 + l * Ff, nullptr, fbb, nullptr,
            Mtot, Ff, Dd, Ff / 128, 0);
        // FFN2: split-K=2, one dispatch, 256 blocks, nk=16
        mfma_gemm<0, 0, 0, 2><<<2 * (Dd / 128) * (Mtot / 128), 256, 0, stream>>>(
            fbb, W2T + (size_t)l * Dd * Ff, b2 + l * Dd, pbx, nullptr, nullptr,
            Mtot, Dd, Ff, Dd / 128, PS);
        // last layer: fuse final lnf into ln2
        ln_kernel<<<Mtot / 4, 256, 0, stream>>>(h, pbx, 2, ln2_s + l * Dd, ln2_b + l * Dd,
                                                (l == Ll - 1) ? lnf_s : nullptr,
                                                (l == Ll - 1) ? lnf_b : nullptr, hb);
    }

    mfma_gemm256<<<(Vv / 256) * (Mtot / 256), 512, 0, stream>>>(
        hb, WlT, bl, (float*)d_out, Mtot, Vv, Dd, Mtot / 256);
}

// Round 10
// 755.653 us; speedup vs baseline: 1.0263x; 1.0263x over previous
//
#include <hip/hip_runtime.h>
#include <math.h>

#define Mtot 4096   // B*T
#define Dd   512
#define Hh   8
#define DKk  64
#define TT   1024
#define Ff   2048
#define Ll   4
#define Vv   32000

typedef __attribute__((ext_vector_type(8))) short bf16x8;
typedef __attribute__((ext_vector_type(4))) float f32x4;
typedef unsigned short u16;

__device__ __forceinline__ u16 f2b(float f) {
    union { float f; unsigned u; } x; x.f = f;
    unsigned r = x.u + 0x7fffu + ((x.u >> 16) & 1u);
    return (u16)(r >> 16);
}

typedef const __attribute__((address_space(1))) unsigned int* gp_t;
typedef __attribute__((address_space(3))) unsigned int* lp_t;
#define GLOAD_LDS16(g, l) __builtin_amdgcn_global_load_lds((gp_t)(const void*)(g), (lp_t)(void*)(l), 16, 0, 0)
#define SBAR  __builtin_amdgcn_s_barrier()
#define SCHED0 __builtin_amdgcn_sched_barrier(0)

// attention LDS swizzle (u16-index space; rows are 64 bf16 = 128 B)
#define SWZ(row, c)  ((c) ^ (((row) & 7) << 3))

// ---------------- fused prep: weight transposes + bias pack + embed+PE ----------------
__global__ __launch_bounds__(256) void prep_kernel(const float* __restrict__ Wq, const float* __restrict__ Wk,
                                                   const float* __restrict__ Wv, const float* __restrict__ Wo,
                                                   const float* __restrict__ W1, const float* __restrict__ W2,
                                                   const float* __restrict__ Wl,
                                                   u16* __restrict__ WqkvT, u16* __restrict__ WoT,
                                                   u16* __restrict__ W1T, u16* __restrict__ W2T,
                                                   u16* __restrict__ WlT,
                                                   const float* __restrict__ bq, const float* __restrict__ bk,
                                                   const float* __restrict__ bv, float* __restrict__ bqkv,
                                                   const int* __restrict__ x, const float* __restrict__ emw,
                                                   float* __restrict__ h, u16* __restrict__ hb) {
    int id = blockIdx.x;
    if (id >= 28312) {            // ---- embed + positional encoding (8192 blocks) ----
        int idx = (id - 28312) * 256 + threadIdx.x;
        int d  = idx & (Dd - 1);
        int bt = idx >> 9;
        int t  = bt & (TT - 1);
        int tok = x[bt];
        float val = (tok == 0) ? 0.0f : emw[(size_t)tok * Dd + d];
        int de = d & ~1;
        float ang = (float)t * expf((float)de * (-9.210340371976184f / (float)Dd));
        val += (d & 1) ? cosf(ang) : sinf(ang);
        h[idx] = val;
        hb[idx] = f2b(val);
        return;
    }
    if (id >= 28288) {            // ---- bias pack (24 blocks) ----
        int idx = (id - 28288) * 256 + threadIdx.x;
        int l = idx / 1536, j = idx - l * 1536;
        float v = (j < 512) ? bq[l * 512 + j] : (j < 1024) ? bk[l * 512 + j - 512] : bv[l * 512 + j - 1024];
        bqkv[idx] = v;
        return;
    }
    // ---- weight transpose: src[K][N] f32 -> dst[N][K] bf16 ----
    __shared__ float t[32][33];
    const float* src; u16* dst; int K, N, tx, ty;
    if (id < 12288) {
        int l = id / 3072, r = id - l * 3072;
        if (r < 768) {
            int which = r >> 8, t2 = r & 255;
            src = (which == 0 ? Wq : which == 1 ? Wk : Wv) + (size_t)l * 262144;
            dst = WqkvT + (size_t)l * 786432 + (size_t)which * 262144;
            K = 512; N = 512; ty = t2 >> 4; tx = t2 & 15;
        } else if (r < 1024) {
            int t2 = r - 768;
            src = Wo + (size_t)l * 262144; dst = WoT + (size_t)l * 262144;
            K = 512; N = 512; ty = t2 >> 4; tx = t2 & 15;
        } else if (r < 2048) {
            int t2 = r - 1024;
            src = W1 + (size_t)l * 1048576; dst = W1T + (size_t)l * 1048576;
            K = 512; N = 2048; ty = t2 >> 6; tx = t2 & 63;
        } else {
            int t2 = r - 2048;
            src = W2 + (size_t)l * 1048576; dst = W2T + (size_t)l * 1048576;
            K = 2048; N = 512; ty = t2 >> 4; tx = t2 & 15;
        }
    } else {
        int t2 = id - 12288;
        src = Wl; dst = WlT; K = 512; N = 32000;
        ty = t2 / 1000; tx = t2 - ty * 1000;
    }
    int n0 = tx * 32, k0 = ty * 32;
    int tid = threadIdx.x, c = tid & 31, rr = tid >> 5;
    #pragma unroll
    for (int i = 0; i < 4; i++)
        t[rr + i * 8][c] = src[(size_t)(k0 + rr + i * 8) * N + n0 + c];
    __syncthreads();
    #pragma unroll
    for (int i = 0; i < 4; i++)
        dst[(size_t)(n0 + rr + i * 8) * K + k0 + c] = f2b(t[c][rr + i * 8]);
}

// ---------------- bf16 MFMA GEMM v3: 4 waves, 128x128 tile, BK=64, ring-2 counted-vmcnt ----------------
// Operand-swapped MFMA: lane holds 1 M-row x 4 consecutive N-cols per fragment -> vectorized C-stores.
template<int ACT, int OUTB, int QKVMODE, int SPLITK>
__global__ __launch_bounds__(256, 2) void mfma_gemm(const u16* __restrict__ A,
                                                    const u16* __restrict__ BT,
                                                    const float* __restrict__ bias,
                                                    float* __restrict__ outF,
                                                    u16* __restrict__ outB,
                                                    u16* __restrict__ vtb,
                                                    int M, int N, int K, int gx, int PS) {
    __shared__ __align__(16) u16 As[2][128 * 64];
    __shared__ __align__(16) u16 Bs[2][128 * 64];
    int tid = threadIdx.x;
    int lane = tid & 63, w = tid >> 6;
    int nwg = gridDim.x, flat = blockIdx.x;
    int wg = (flat & 7) * (nwg >> 3) + (flat >> 3);   // bijective XCD swizzle (nwg%8==0)
    int ks = 0, sub = wg;
    if (SPLITK > 1) {
        int tps = gx * (M >> 7);
        ks = wg / tps; sub = wg - ks * tps;
    }
    int bm = sub / gx, bn = sub - bm * gx;
    int kb = ks * (K / SPLITK);
    int wr = w >> 1, wc = w & 1;                      // wave grid 2x2 -> 64x64 per wave
    int fr = lane & 15, fq = lane >> 4;

    int sr = lane >> 3, sc = lane & 7;
    int scol = (sc ^ sr) * 8;                         // pre-swizzled source chunk
    const u16* Ab = A  + (size_t)(bm * 128 + w * 32 + sr) * K + kb + scol;
    const u16* Bb = BT + (size_t)(bn * 128 + w * 32 + sr) * K + kb + scol;
    u16* lA = &As[0][0] + w * 2048;
    u16* lB = &Bs[0][0] + w * 2048;

    f32x4 acc[4][4] = {};
    int nk = (K / SPLITK) >> 6;

#define STAGE(buf, kt)                                                     \
    {   int ko = (kt) * 64;                                                \
        GLOAD_LDS16(Ab + ko,          lA + (buf) * (128 * 64));            \
        GLOAD_LDS16(Ab + 8 * K + ko,  lA + (buf) * (128 * 64) + 512);      \
        GLOAD_LDS16(Ab + 16 * K + ko, lA + (buf) * (128 * 64) + 1024);     \
        GLOAD_LDS16(Ab + 24 * K + ko, lA + (buf) * (128 * 64) + 1536);     \
        GLOAD_LDS16(Bb + ko,          lB + (buf) * (128 * 64));            \
        GLOAD_LDS16(Bb + 8 * K + ko,  lB + (buf) * (128 * 64) + 512);      \
        GLOAD_LDS16(Bb + 16 * K + ko, lB + (buf) * (128 * 64) + 1024);     \
        GLOAD_LDS16(Bb + 24 * K + ko, lB + (buf) * (128 * 64) + 1536); }

    STAGE(0, 0);
    STAGE(1, 1);

    int cur = 0;
    for (int kt = 0; kt < nk; kt++) {
        if (kt + 1 < nk) { asm volatile("s_waitcnt vmcnt(8)" ::: "memory"); }
        else             { asm volatile("s_waitcnt vmcnt(0)" ::: "memory"); }
        SBAR;
        SCHED0;
        bf16x8 a[4][2], b[4][2];
        #pragma unroll
        for (int m = 0; m < 4; m++) {
            int row = wr * 64 + m * 16 + fr;
            a[m][0] = *(const bf16x8*)&As[cur][row * 64 + ((fq ^ (row & 7)) * 8)];
            a[m][1] = *(const bf16x8*)&As[cur][row * 64 + (((fq + 4) ^ (row & 7)) * 8)];
        }
        #pragma unroll
        for (int n = 0; n < 4; n++) {
            int row = wc * 64 + n * 16 + fr;
            b[n][0] = *(const bf16x8*)&Bs[cur][row * 64 + ((fq ^ (row & 7)) * 8)];
            b[n][1] = *(const bf16x8*)&Bs[cur][row * 64 + (((fq + 4) ^ (row & 7)) * 8)];
        }
        __builtin_amdgcn_s_setprio(1);
        #pragma unroll
        for (int m = 0; m < 4; m++)
            #pragma unroll
            for (int n = 0; n < 4; n++) {
                acc[m][n] = __builtin_amdgcn_mfma_f32_16x16x32_bf16(b[n][0], a[m][0], acc[m][n], 0, 0, 0);
                acc[m][n] = __builtin_amdgcn_mfma_f32_16x16x32_bf16(b[n][1], a[m][1], acc[m][n], 0, 0, 0);
            }
        __builtin_amdgcn_s_setprio(0);
        SCHED0;
        SBAR;
        SCHED0;
        if (kt + 2 < nk) STAGE(cur, kt + 2);
        cur ^= 1;
    }
#undef STAGE

    // epilogue: lane owns M-row = ...+m*16+fr, N-cols = ...+n*16+fq*4 .. +3
    #pragma unroll
    for (int m = 0; m < 4; m++) {
        int row = bm * 128 + wr * 64 + m * 16 + fr;
        #pragma unroll
        for (int n = 0; n < 4; n++) {
            int col0 = bn * 128 + wc * 64 + n * 16 + fq * 4;
            if (QKVMODE && bn >= 8) {                  // V columns -> transposed scatter
                int bb = row >> 10, t = row & 1023;
                #pragma unroll
                for (int r = 0; r < 4; r++) {
                    int d = col0 + r - 1024;
                    int hh = d >> 6, dd = d & 63;
                    vtb[(((size_t)bb * Hh + hh) * 64 + dd) * 1024 + t] = f2b(acc[m][n][r] + bias[col0 + r]);
                }
            } else {
                f32x4 v = acc[m][n];
                if (bias && ks == 0) v += *(const f32x4*)&bias[col0];
                if (ACT == 1) {
                    #pragma unroll
                    for (int r = 0; r < 4; r++) v[r] = 0.5f * v[r] * (1.0f + erff(v[r] * 0.7071067811865475f));
                }
                if (OUTB) {
                    union { unsigned long long ull; u16 s[4]; } pk;
                    #pragma unroll
                    for (int r = 0; r < 4; r++) pk.s[r] = f2b(v[r]);
                    *(unsigned long long*)&outB[(size_t)row * N + col0] = pk.ull;
                } else {
                    *(f32x4*)&outF[(size_t)ks * PS + (size_t)row * N + col0] = v;
                }
            }
        }
    }
}

// ---------------- bf16 MFMA GEMM 256x256: 8 waves, BK=64, ring-2 (logits) ----------------
__global__ __launch_bounds__(512, 1) void mfma_gemm256(const u16* __restrict__ A,
                                                       const u16* __restrict__ BT,
                                                       const float* __restrict__ bias,
                                                       float* __restrict__ outF,
                                                       int M, int N, int K, int gy) {
    __shared__ __align__(16) u16 As[2][256 * 64];
    __shared__ __align__(16) u16 Bs[2][256 * 64];
    int tid = threadIdx.x;
    int lane = tid & 63, w = tid >> 6;
    int nwg = gridDim.x, flat = blockIdx.x;
    int wg = (flat & 7) * (nwg >> 3) + (flat >> 3);
    int bm = wg & (gy - 1), bn = wg >> 4;             // column-major (gy==16)
    int wr = w >> 2, wc = w & 3;
    int fr = lane & 15, fq = lane >> 4;

    int sr8 = lane >> 3, sc = lane & 7;
    int scol = (sc ^ sr8) * 8;
    const u16* Ab = A  + (size_t)(bm * 256 + w * 32 + sr8) * K + scol;
    const u16* Bb = BT + (size_t)(bn * 256 + w * 32 + sr8) * K + scol;

    f32x4 acc[8][4] = {};
    int nk = K >> 6;

#define STAGE256(buf, kt)                                                    \
    {   int ko = (kt) * 64;                                                  \
        GLOAD_LDS16(Ab + ko,          &As[buf][(w * 32 +  0) * 64]);         \
        GLOAD_LDS16(Ab + 8 * K + ko,  &As[buf][(w * 32 +  8) * 64]);         \
        GLOAD_LDS16(Ab + 16 * K + ko, &As[buf][(w * 32 + 16) * 64]);         \
        GLOAD_LDS16(Ab + 24 * K + ko, &As[buf][(w * 32 + 24) * 64]);         \
        GLOAD_LDS16(Bb + ko,          &Bs[buf][(w * 32 +  0) * 64]);         \
        GLOAD_LDS16(Bb + 8 * K + ko,  &Bs[buf][(w * 32 +  8) * 64]);         \
        GLOAD_LDS16(Bb + 16 * K + ko, &Bs[buf][(w * 32 + 16) * 64]);         \
        GLOAD_LDS16(Bb + 24 * K + ko, &Bs[buf][(w * 32 + 24) * 64]); }

    STAGE256(0, 0);
    STAGE256(1, 1);

    int cur = 0;
    for (int kt = 0; kt < nk; kt++) {
        if (kt + 1 < nk) { asm volatile("s_waitcnt vmcnt(8)" ::: "memory"); }
        else             { asm volatile("s_waitcnt vmcnt(0)" ::: "memory"); }
        SBAR;
        SCHED0;
        bf16x8 b[4][2];
        #pragma unroll
        for (int n = 0; n < 4; n++) {
            int row = wc * 64 + n * 16 + fr;
            b[n][0] = *(const bf16x8*)&Bs[cur][row * 64 + ((fq ^ (row & 7)) * 8)];
            b[n][1] = *(const bf16x8*)&Bs[cur][row * 64 + (((fq + 4) ^ (row & 7)) * 8)];
        }
        #pragma unroll
        for (int m = 0; m < 8; m++) {
            int row = wr * 128 + m * 16 + fr;
            bf16x8 a0 = *(const bf16x8*)&As[cur][row * 64 + ((fq ^ (row & 7)) * 8)];
            bf16x8 a1 = *(const bf16x8*)&As[cur][row * 64 + (((fq + 4) ^ (row & 7)) * 8)];
            __builtin_amdgcn_s_setprio(1);
            #pragma unroll
            for (int n = 0; n < 4; n++) {
                acc[m][n] = __builtin_amdgcn_mfma_f32_16x16x32_bf16(b[n][0], a0, acc[m][n], 0, 0, 0);
                acc[m][n] = __builtin_amdgcn_mfma_f32_16x16x32_bf16(b[n][1], a1, acc[m][n], 0, 0, 0);
            }
            __builtin_amdgcn_s_setprio(0);
        }
        SCHED0;
        SBAR;
        SCHED0;
        if (kt + 2 < nk) STAGE256(cur, kt + 2);
        cur ^= 1;
    }
#undef STAGE256

    #pragma unroll
    for (int m = 0; m < 8; m++) {
        int row = bm * 256 + wr * 128 + m * 16 + fr;
        #pragma unroll
        for (int n = 0; n < 4; n++) {
            int col0 = bn * 256 + wc * 64 + n * 16 + fq * 4;
            f32x4 v = acc[m][n] + *(const f32x4*)&bias[col0];
            *(f32x4*)&outF[(size_t)row * N + col0] = v;
        }
    }
}

// ---------------- MFMA flash attention: QBLK=64 (4 waves x 16 rows), KVBLK=64 ----------------
__global__ __launch_bounds__(256) void attn_mfma(const u16* __restrict__ qkv,
                                                 const u16* __restrict__ vtb,
                                                 u16* __restrict__ ob) {
    int qt = (int)gridDim.x - 1 - (int)blockIdx.x;
    int hh = blockIdx.y, b = blockIdx.z;
    __shared__ __align__(16) u16 Qs[64 * 64];
    __shared__ __align__(16) u16 Ks[64 * 64];
    __shared__ __align__(16) u16 Vs[64 * 64];
    __shared__ __align__(16) u16 Ps[4][16 * 64];
    int tid = threadIdx.x;
    int lane = tid & 63, w = tid >> 6;
    int fr = lane & 15, fq = lane >> 4;
    int q0 = qt * 64;
    int sr = tid >> 2, sc0 = (tid & 3) * 16;

    bf16x8 rk0, rk1, rv0, rv1;
    bf16x8 sk0, sk1, sv0, sv1;

    auto load_a = [&](int kt) {
        const u16* srcK = qkv + ((size_t)(b * TT + kt * 64 + sr)) * 1536 + 512 + hh * 64 + sc0;
        rk0 = *(const bf16x8*)srcK; rk1 = *(const bf16x8*)(srcK + 8);
        const u16* srcV = vtb + (((size_t)(b * Hh + hh)) * 64 + sr) * 1024 + kt * 64 + sc0;
        rv0 = *(const bf16x8*)srcV; rv1 = *(const bf16x8*)(srcV + 8);
    };
    auto load_b = [&](int kt) {
        const u16* srcK = qkv + ((size_t)(b * TT + kt * 64 + sr)) * 1536 + 512 + hh * 64 + sc0;
        sk0 = *(const bf16x8*)srcK; sk1 = *(const bf16x8*)(srcK + 8);
        const u16* srcV = vtb + (((size_t)(b * Hh + hh)) * 64 + sr) * 1024 + kt * 64 + sc0;
        sv0 = *(const bf16x8*)srcV; sv1 = *(const bf16x8*)(srcV + 8);
    };
    auto store_a = [&]() {
        *(bf16x8*)&Ks[sr * 64 + SWZ(sr, sc0)]     = rk0;
        *(bf16x8*)&Ks[sr * 64 + SWZ(sr, sc0 + 8)] = rk1;
        *(bf16x8*)&Vs[sr * 64 + SWZ(sr, sc0)]     = rv0;
        *(bf16x8*)&Vs[sr * 64 + SWZ(sr, sc0 + 8)] = rv1;
    };
    auto store_b = [&]() {
        *(bf16x8*)&Ks[sr * 64 + SWZ(sr, sc0)]     = sk0;
        *(bf16x8*)&Ks[sr * 64 + SWZ(sr, sc0 + 8)] = sk1;
        *(bf16x8*)&Vs[sr * 64 + SWZ(sr, sc0)]     = sv0;
        *(bf16x8*)&Vs[sr * 64 + SWZ(sr, sc0 + 8)] = sv1;
    };

    load_a(0);
    {
        const u16* src = qkv + ((size_t)(b * TT + q0 + sr)) * 1536 + hh * 64 + sc0;
        bf16x8 v0 = *(const bf16x8*)src;
        bf16x8 v1 = *(const bf16x8*)(src + 8);
        *(bf16x8*)&Qs[sr * 64 + SWZ(sr, sc0)]     = v0;
        *(bf16x8*)&Qs[sr * 64 + SWZ(sr, sc0 + 8)] = v1;
    }
    __syncthreads();
    bf16x8 aq0 = *(const bf16x8*)&Qs[(w * 16 + fr) * 64 + SWZ(w * 16 + fr, fq * 8)];
    bf16x8 aq1 = *(const bf16x8*)&Qs[(w * 16 + fr) * 64 + SWZ(w * 16 + fr, 32 + fq * 8)];

    f32x4 oa[4] = {};
    float mreg[4], lreg[4];
    #pragma unroll
    for (int i = 0; i < 4; i++) { mreg[i] = -1e30f; lreg[i] = 0.0f; }

    auto compute_tile = [&](int kt) {
        f32x4 sa[4] = {};
        __builtin_amdgcn_s_setprio(1);
        #pragma unroll
        for (int nt = 0; nt < 4; nt++) {
            int krow = nt * 16 + fr;
            bf16x8 b0 = *(const bf16x8*)&Ks[krow * 64 + SWZ(krow, fq * 8)];
            bf16x8 b1 = *(const bf16x8*)&Ks[krow * 64 + SWZ(krow, 32 + fq * 8)];
            sa[nt] = __builtin_amdgcn_mfma_f32_16x16x32_bf16(aq0, b0, sa[nt], 0, 0, 0);
            sa[nt] = __builtin_amdgcn_mfma_f32_16x16x32_bf16(aq1, b1, sa[nt], 0, 0, 0);
        }
        __builtin_amdgcn_s_setprio(0);

        float p[4][4];
        int qg = w * 16 + fq * 4;
        bool diag = (kt == qt);
        #pragma unroll
        for (int nt = 0; nt < 4; nt++)
            #pragma unroll
            for (int i = 0; i < 4; i++) {
                float s = sa[nt][i] * 0.125f;
                if (diag && (nt * 16 + fr > qg + i)) s = -1e30f;
                p[nt][i] = s;
            }

        float mnew[4], fscale[4];
        #pragma unroll
        for (int i = 0; i < 4; i++) {
            float v = fmaxf(fmaxf(p[0][i], p[1][i]), fmaxf(p[2][i], p[3][i]));
            v = fmaxf(v, __shfl_xor(v, 1));
            v = fmaxf(v, __shfl_xor(v, 2));
            v = fmaxf(v, __shfl_xor(v, 4));
            v = fmaxf(v, __shfl_xor(v, 8));
            mnew[i] = fmaxf(mreg[i], v);
            fscale[i] = __expf(mreg[i] - mnew[i]);
            mreg[i] = mnew[i];
        }
        #pragma unroll
        for (int i = 0; i < 4; i++) {
            float sum = 0.f;
            #pragma unroll
            for (int nt = 0; nt < 4; nt++) {
                float e = __expf(p[nt][i] - mnew[i]);
                p[nt][i] = e;
                sum += e;
            }
            sum += __shfl_xor(sum, 1);
            sum += __shfl_xor(sum, 2);
            sum += __shfl_xor(sum, 4);
            sum += __shfl_xor(sum, 8);
            lreg[i] = lreg[i] * fscale[i] + sum;
        }
        #pragma unroll
        for (int nn = 0; nn < 4; nn++)
            #pragma unroll
            for (int i = 0; i < 4; i++)
                oa[nn][i] *= fscale[i];

        u16* ps = &Ps[w][0];
        #pragma unroll
        for (int nt = 0; nt < 4; nt++)
            #pragma unroll
            for (int i = 0; i < 4; i++) {
                int row = fq * 4 + i, col = nt * 16 + fr;
                ps[row * 64 + SWZ(row, col)] = f2b(p[nt][i]);
            }
        bf16x8 pa0 = *(const bf16x8*)&ps[fr * 64 + SWZ(fr, fq * 8)];
        bf16x8 pa1 = *(const bf16x8*)&ps[fr * 64 + SWZ(fr, 32 + fq * 8)];
        __builtin_amdgcn_s_setprio(1);
        #pragma unroll
        for (int nn = 0; nn < 4; nn++) {
            int drow = nn * 16 + fr;
            bf16x8 vb0 = *(const bf16x8*)&Vs[drow * 64 + SWZ(drow, fq * 8)];
            bf16x8 vb1 = *(const bf16x8*)&Vs[drow * 64 + SWZ(drow, 32 + fq * 8)];
            oa[nn] = __builtin_amdgcn_mfma_f32_16x16x32_bf16(pa0, vb0, oa[nn], 0, 0, 0);
            oa[nn] = __builtin_amdgcn_mfma_f32_16x16x32_bf16(pa1, vb1, oa[nn], 0, 0, 0);
        }
        __builtin_amdgcn_s_setprio(0);
    };

    int kt = 0;
    for (;;) {
        SCHED0; SBAR;
        store_a();
        if (kt + 1 <= qt) load_b(kt + 1);
        asm volatile("s_waitcnt lgkmcnt(0)" ::: "memory");
        SBAR; SCHED0;
        compute_tile(kt);
        if (++kt > qt) break;

        SCHED0; SBAR;
        store_b();
        if (kt + 1 <= qt) load_a(kt + 1);
        asm volatile("s_waitcnt lgkmcnt(0)" ::: "memory");
        SBAR; SCHED0;
        compute_tile(kt);
        if (++kt > qt) break;
    }

    #pragma unroll
    for (int i = 0; i < 4; i++) {
        float inv = 1.0f / lreg[i];
        size_t row = (size_t)(b * TT + q0 + w * 16 + fq * 4 + i) * Dd + hh * 64;
        #pragma unroll
        for (int nn = 0; nn < 4; nn++)
            ob[row + nn * 16 + fr] = f2b(oa[nn][i] * inv);
    }
}

// ---------------- residual add (np split-K partials) + LayerNorm (+optional 2nd LN), wave-per-row ----------------
__global__ __launch_bounds__(256) void ln_kernel(float* __restrict__ h,
                                                 const float* __restrict__ pp, int np,
                                                 const float* __restrict__ gs,
                                                 const float* __restrict__ gb,
                                                 const float* __restrict__ gs2,
                                                 const float* __restrict__ gb2,
                                                 u16* __restrict__ hb) {
    int w = threadIdx.x >> 6, lane = threadIdx.x & 63;
    int row = (blockIdx.x << 2) + w;
    size_t base = (size_t)row * Dd + lane * 8;
    const size_t PART = (size_t)Mtot * Dd;
    f32x4 v0 = *(const f32x4*)&h[base];
    f32x4 v1 = *(const f32x4*)&h[base + 4];
    for (int p = 0; p < np; p++) {
        const float* d = pp + (size_t)p * PART;
        v0 += *(const f32x4*)&d[base];
        v1 += *(const f32x4*)&d[base + 4];
    }
    float s = v0[0] + v0[1] + v0[2] + v0[3] + v1[0] + v1[1] + v1[2] + v1[3];
    #pragma unroll
    for (int st = 1; st < 64; st <<= 1) s += __shfl_xor(s, st);
    float m = s * (1.0f / Dd);
    float q = 0.f;
    #pragma unroll
    for (int j = 0; j < 4; j++) { float a = v0[j] - m, b = v1[j] - m; q += a * a + b * b; }
    #pragma unroll
    for (int st = 1; st < 64; st <<= 1) q += __shfl_xor(q, st);
    float r = rsqrtf(q * (1.0f / Dd) + 1e-5f);
    f32x4 g0 = *(const f32x4*)&gs[lane * 8],     g1 = *(const f32x4*)&gs[lane * 8 + 4];
    f32x4 c0 = *(const f32x4*)&gb[lane * 8],     c1 = *(const f32x4*)&gb[lane * 8 + 4];
    f32x4 y0, y1;
    #pragma unroll
    for (int j = 0; j < 4; j++) {
        y0[j] = (v0[j] - m) * r * g0[j] + c0[j];
        y1[j] = (v1[j] - m) * r * g1[j] + c1[j];
    }
    if (gs2) {   // fused second LayerNorm (lnf)
        float s2 = y0[0] + y0[1] + y0[2] + y0[3] + y1[0] + y1[1] + y1[2] + y1[3];
        #pragma unroll
        for (int st = 1; st < 64; st <<= 1) s2 += __shfl_xor(s2, st);
        float m2 = s2 * (1.0f / Dd);
        float q2 = 0.f;
        #pragma unroll
        for (int j = 0; j < 4; j++) { float a = y0[j] - m2, b = y1[j] - m2; q2 += a * a + b * b; }
        #pragma unroll
        for (int st = 1; st < 64; st <<= 1) q2 += __shfl_xor(q2, st);
        float r2 = rsqrtf(q2 * (1.0f / Dd) + 1e-5f);
        f32x4 h0 = *(const f32x4*)&gs2[lane * 8], h1 = *(const f32x4*)&gs2[lane * 8 + 4];
        f32x4 d0 = *(const f32x4*)&gb2[lane * 8], d1 = *(const f32x4*)&gb2[lane * 8 + 4];
        #pragma unroll
        for (int j = 0; j < 4; j++) {
            y0[j] = (y0[j] - m2) * r2 * h0[j] + d0[j];
            y1[j] = (y1[j] - m2) * r2 * h1[j] + d1[j];
        }
    }
    bf16x8 yb;
    #pragma unroll
    for (int j = 0; j < 4; j++) {
        yb[j]     = (short)f2b(y0[j]);
        yb[j + 4] = (short)f2b(y1[j]);
    }
    *(f32x4*)&h[base]     = y0;
    *(f32x4*)&h[base + 4] = y1;
    *(bf16x8*)&hb[base]   = yb;
}

extern "C" void kernel_launch(void* const* d_in, const int* in_sizes, int n_in,
                              void* d_out, int out_size, void* d_ws, size_t ws_size,
                              hipStream_t stream) {
    const int*   x     = (const int*)  d_in[0];
    const float* embed = (const float*)d_in[1];
    const float* Wq    = (const float*)d_in[2];
    const float* bq    = (const float*)d_in[3];
    const float* Wk    = (const float*)d_in[4];
    const float* bk    = (const float*)d_in[5];
    const float* Wv    = (const float*)d_in[6];
    const float* bv    = (const float*)d_in[7];
    const float* Wo    = (const float*)d_in[8];
    const float* bo    = (const float*)d_in[9];
    const float* ln1_s = (const float*)d_in[10];
    const float* ln1_b = (const float*)d_in[11];
    const float* W1    = (const float*)d_in[12];
    const float* b1    = (const float*)d_in[13];
    const float* W2    = (const float*)d_in[14];
    const float* b2    = (const float*)d_in[15];
    const float* ln2_s = (const float*)d_in[16];
    const float* ln2_b = (const float*)d_in[17];
    const float* lnf_s = (const float*)d_in[18];
    const float* lnf_b = (const float*)d_in[19];
    const float* Wl    = (const float*)d_in[20];
    const float* bl    = (const float*)d_in[21];

    // ---- workspace layout ----
    char* wp = (char*)d_ws;
    float* h    = (float*)wp;  wp += (size_t)Mtot * Dd * 4;       //  8 MB
    u16*   hb   = (u16*)wp;    wp += (size_t)Mtot * Dd * 2;       //  4 MB
    u16*   qkvb = (u16*)wp;    wp += (size_t)Mtot * 1536 * 2;     // 12.6 MB
    u16*   vtb  = (u16*)wp;    wp += (size_t)Mtot * Dd * 2;       //  4 MB  [B][H][64][1024]
    u16*   obb  = (u16*)wp;    wp += (size_t)Mtot * Dd * 2;       //  4 MB
    u16*   fbb  = (u16*)wp;    wp += (size_t)Mtot * Ff * 2;       // 16 MB
    u16*   WlT  = (u16*)wp;    wp += (size_t)Vv * Dd * 2;         // 33 MB
    float* bqkv = (float*)wp;  wp += (size_t)Ll * 1536 * 4;       // 24 KB

    // ---- transient data in d_out (dead before final logits GEMM writes it) ----
    char* op = (char*)d_out;
    u16* WqkvT = (u16*)op;  op += (size_t)Ll * 1536 * Dd * 2;
    u16* WoT   = (u16*)op;  op += (size_t)Ll * Dd * Dd * 2;
    u16* W1T   = (u16*)op;  op += (size_t)Ll * Ff * Dd * 2;
    u16* W2T   = (u16*)op;  op += (size_t)Ll * Dd * Ff * 2;
    float* pbx = (float*)op; op += (size_t)4 * Mtot * Dd * 4;     // 32 MB split-K partials

    prep_kernel<<<36504, 256, 0, stream>>>(Wq, Wk, Wv, Wo, W1, W2, Wl,
                                           WqkvT, WoT, W1T, W2T, WlT,
                                           bq, bk, bv, bqkv, x, embed, h, hb);

    const int PS = Mtot * Dd;   // fp32 elements per split partial

    for (int l = 0; l < Ll; l++) {
        mfma_gemm<0, 1, 1, 1><<<(1536 / 128) * (Mtot / 128), 256, 0, stream>>>(
            hb, WqkvT + (size_t)l * 1536 * Dd, bqkv + l * 1536, nullptr, qkvb, vtb,
            Mtot, 1536, Dd, 1536 / 128, 0);
        attn_mfma<<<dim3(TT / 64, Hh, 4), 256, 0, stream>>>(qkvb, vtb, obb);
        // O-proj: split-K=2, one dispatch, 256 blocks
        mfma_gemm<0, 0, 0, 2><<<2 * (Dd / 128) * (Mtot / 128), 256, 0, stream>>>(
            obb, WoT + (size_t)l * Dd * Dd, bo + l * Dd, pbx, nullptr, nullptr,
            Mtot, Dd, Dd, Dd / 128, PS);
        ln_kernel<<<Mtot / 4, 256, 0, stream>>>(h, pbx, 2, ln1_s + l * Dd, ln1_b + l * Dd,
                                                nullptr, nullptr, hb);
        mfma_gemm<1, 1, 0, 1><<<(Ff / 128) * (Mtot / 128), 256, 0, stream>>>(
            hb, W1T + (size_t)l * Ff * Dd, b1 + l * Ff, nullptr, fbb, nullptr,
            Mtot, Ff, Dd, Ff / 128, 0);
        // FFN2: split-K=4, one dispatch, 512 blocks
        mfma_gemm<0, 0, 0, 4><<<4 * (Dd / 128) * (Mtot / 128), 256, 0, stream>>>(
            fbb, W2T + (size_t)l * Dd * Ff, b2 + l * Dd, pbx, nullptr, nullptr,
            Mtot, Dd, Ff, Dd / 128, PS);
        // last layer: fuse final lnf into ln2
        ln_kernel<<<Mtot / 4, 256, 0, stream>>>(h, pbx, 4, ln2_s + l * Dd, ln2_b + l * Dd,
                                                (l == Ll - 1) ? lnf_s : nullptr,
                                                (l == Ll - 1) ? lnf_b : nullptr, hb);
    }

    mfma_gemm256<<<(Vv / 256) * (Mtot / 256), 512, 0, stream>>>(
        hb, WlT, bl, (float*)d_out, Mtot, Vv, Dd, Mtot / 256);
}